// Round 9
// baseline (251.808 us; speedup 1.0000x reference)
//
#include <hip/hip_runtime.h>
#include <hip/hip_bf16.h>

#define B_  2
#define T_  4096
#define C_  768
#define H_  12
#define D_  64
#define MTOT (B_*T_)   // 8192

typedef __bf16 bf16;
typedef __bf16 bf16x8 __attribute__((ext_vector_type(8)));
typedef __bf16 bf16x4 __attribute__((ext_vector_type(4)));
typedef float  f32x4  __attribute__((ext_vector_type(4)));
typedef unsigned int u32x4 __attribute__((ext_vector_type(4)));

// async global->LDS, 16B per lane; LDS dest must be wave-uniform base + lane*16
__device__ __forceinline__ void gl_lds16(const bf16* g, bf16* l) {
    __builtin_amdgcn_global_load_lds(
        (const __attribute__((address_space(1))) void*)g,
        (__attribute__((address_space(3))) void*)l, 16, 0, 0);
}

// ---- P redistribution via permlane-swap BUILTINS ----
__device__ __forceinline__ void pswap32_16(unsigned int& x, unsigned int& y) {
    auto r1 = __builtin_amdgcn_permlane32_swap(x, y, false, false);
    auto r2 = __builtin_amdgcn_permlane16_swap(r1[0], r1[1], false, false);
    x = r2[0]; y = r2[1];
}
__device__ __forceinline__ unsigned int cvtpk(float lo, float hi) {
    unsigned int r;
    asm("v_cvt_pk_bf16_f32 %0, %1, %2" : "=v"(r) : "v"(lo), "v"(hi));
    return r;
}

// ---------------- fp32 -> bf16 convert ----------------
__global__ __launch_bounds__(256) void cvt_bf16(const float* __restrict__ src,
                                                bf16* __restrict__ dst, int n8) {
    int i = blockIdx.x * 256 + threadIdx.x;
    if (i >= n8) return;
    const float4* s4 = (const float4*)src;
    float4 a = s4[2*(size_t)i], b = s4[2*(size_t)i+1];
    bf16x8 o;
    o[0]=(bf16)a.x; o[1]=(bf16)a.y; o[2]=(bf16)a.z; o[3]=(bf16)a.w;
    o[4]=(bf16)b.x; o[5]=(bf16)b.y; o[6]=(bf16)b.z; o[7]=(bf16)b.w;
    *(bf16x8*)(dst + 8*(size_t)i) = o;
}

__global__ __launch_bounds__(256) void cvt_bf16_w4(const float* __restrict__ w0,
                                                   const float* __restrict__ w1,
                                                   const float* __restrict__ w2,
                                                   const float* __restrict__ w3,
                                                   bf16* __restrict__ d0,
                                                   bf16* __restrict__ d1,
                                                   bf16* __restrict__ d2,
                                                   bf16* __restrict__ d3) {
    int z = blockIdx.y;
    const float* src = (z==0)?w0:(z==1)?w1:(z==2)?w2:w3;
    bf16* dst = (z==0)?d0:(z==1)?d1:(z==2)?d2:d3;
    int i = blockIdx.x * 256 + threadIdx.x;
    const float4* s4 = (const float4*)src;
    float4 a = s4[2*(size_t)i], b = s4[2*(size_t)i+1];
    bf16x8 o;
    o[0]=(bf16)a.x; o[1]=(bf16)a.y; o[2]=(bf16)a.z; o[3]=(bf16)a.w;
    o[4]=(bf16)b.x; o[5]=(bf16)b.y; o[6]=(bf16)b.z; o[7]=(bf16)b.w;
    *(bf16x8*)(dst + 8*(size_t)i) = o;
}

// ---------------- QKV projection GEMM (round-9: 3-buf counted-vmcnt) --------
// Round-8 post-mortem: dbuf+__syncthreads was NEUTRAL because __syncthreads
// drains vmcnt(0) — "dbuf with drain0" ~= serial (m218: T3's gain IS T4).
// This round: 3-buffer rotation + raw s_barrier + counted `s_waitcnt vmcnt(4)`
// — wait for the OLDER tile while the newer one stays in flight. Each DMA
// gets a full iteration (~400cy) to land. LDS 48KB -> 3 blocks/CU.
// Also: z<2 epilogue was 64 scalar 2B stores/thread; swapping MFMA operands
// (mfma(bfr,af)) transposes the fragment so regs walk the feature dim ->
// 4 consecutive d pack into bf16x4 stores (64 scalar -> 16 packed).
// z=0 -> Q (pre-scaled by 0.125*log2e) in (B,H,T,D); z=1 -> K; z=2 -> V^T.
__global__ __launch_bounds__(256) void gemm_qkv(const bf16* __restrict__ xb,
                                                const bf16* __restrict__ wqb,
                                                const bf16* __restrict__ wkb,
                                                const bf16* __restrict__ wvb,
                                                bf16* __restrict__ qo,
                                                bf16* __restrict__ ko,
                                                bf16* __restrict__ vto) {
    int z = blockIdx.z;
    const bf16* w = (z == 0) ? wqb : (z == 1) ? wkb : wvb;
    bf16* dst = (z == 0) ? qo : (z == 1) ? ko : vto;
    int mbase = blockIdx.x * 128;
    int nbase = blockIdx.y * 128;
    __shared__ bf16 As[3][128][32];   // UNPADDED: global_load_lds lane-contiguous
    __shared__ bf16 Bs[3][128][32];
    int tid  = threadIdx.x;
    int wave = tid >> 6, lane = tid & 63;
    int wm = (wave >> 1) * 64, wn = (wave & 1) * 64;
    int lr = lane & 15, lg = lane >> 4;
    int srow0 = tid >> 2, scol0 = tid & 3;
    int srow1 = (tid + 256) >> 2, scol1 = (tid + 256) & 3;
    const bf16* xa0 = xb + (size_t)(mbase + srow0) * C_ + scol0 * 8;
    const bf16* xa1 = xb + (size_t)(mbase + srow1) * C_ + scol1 * 8;
    const bf16* wa0 = w  + (size_t)(nbase + srow0) * C_ + scol0 * 8;
    const bf16* wa1 = w  + (size_t)(nbase + srow1) * C_ + scol1 * 8;
#define GSTAGE(kb_, cb_) do { \
        gl_lds16(xa0 + (kb_), &As[cb_][srow0][scol0 * 8]); \
        gl_lds16(xa1 + (kb_), &As[cb_][srow1][scol1 * 8]); \
        gl_lds16(wa0 + (kb_), &Bs[cb_][srow0][scol0 * 8]); \
        gl_lds16(wa1 + (kb_), &Bs[cb_][srow1][scol1 * 8]); \
    } while (0)
    f32x4 acc[4][4] = {};
    GSTAGE(0, 0);
    GSTAGE(32, 1);
    asm volatile("s_waitcnt vmcnt(4)" ::: "memory");   // tile 0 landed, tile 1 in flight
    __builtin_amdgcn_s_barrier();
    int cur = 0, stg = 2;                              // stg = buffer for tile t+2
    for (int t = 0; t < 24; ++t) {
        if (t + 2 < 24) GSTAGE((t + 2) * 32, stg);     // issue BEFORE compute
        bf16x8 af[4], bfr[4];
        #pragma unroll
        for (int mt = 0; mt < 4; ++mt) af[mt]  = *(const bf16x8*)(&As[cur][wm + mt*16 + lr][lg*8]);
        #pragma unroll
        for (int nt = 0; nt < 4; ++nt) bfr[nt] = *(const bf16x8*)(&Bs[cur][wn + nt*16 + lr][lg*8]);
        if (z < 2) {            // transposed acc: regs -> n (feature), lane -> m
            #pragma unroll
            for (int mt = 0; mt < 4; ++mt)
                #pragma unroll
                for (int nt = 0; nt < 4; ++nt)
                    acc[mt][nt] = __builtin_amdgcn_mfma_f32_16x16x32_bf16(bfr[nt], af[mt], acc[mt][nt], 0, 0, 0);
        } else {                // normal acc: regs -> m, lane -> n
            #pragma unroll
            for (int mt = 0; mt < 4; ++mt)
                #pragma unroll
                for (int nt = 0; nt < 4; ++nt)
                    acc[mt][nt] = __builtin_amdgcn_mfma_f32_16x16x32_bf16(af[mt], bfr[nt], acc[mt][nt], 0, 0, 0);
        }
        if (t + 2 < 24) {
            asm volatile("s_waitcnt vmcnt(4)" ::: "memory");  // t+1 landed, t+2 flying
            __builtin_amdgcn_s_barrier();
        } else if (t + 1 < 24) {
            asm volatile("s_waitcnt vmcnt(0)" ::: "memory");  // final tile landed
            __builtin_amdgcn_s_barrier();
        }
        cur = (cur == 2) ? 0 : cur + 1;
        stg = (stg == 2) ? 0 : stg + 1;
    }
#undef GSTAGE
    float sc = (z == 0) ? 0.18033688011112042f : 1.0f;  // 0.125*log2(e) folded into Q
    if (z < 2) {
        // transposed: m = token from lane, n = feature from regs -> packed d-stores
        int m0 = mbase + wm + lr;
        int n0 = nbase + wn + (lg << 2);
        #pragma unroll
        for (int mt = 0; mt < 4; ++mt) {
            int m = m0 + mt * 16;
            int b = m >> 12, t = m & 4095;
            #pragma unroll
            for (int nt = 0; nt < 4; ++nt) {
                int n = n0 + nt * 16;
                int h = n >> 6, d = n & 63;
                bf16x4 pk;
                #pragma unroll
                for (int r = 0; r < 4; ++r) pk[r] = (bf16)(acc[mt][nt][r] * sc);
                *(bf16x4*)(dst + (((size_t)b * H_ + h) * T_ + t) * 64 + d) = pk;
            }
        }
    } else {
        int m0 = mbase + wm + (lg << 2);
        int n0 = nbase + wn + lr;
        #pragma unroll
        for (int mt = 0; mt < 4; ++mt) {
            int m = m0 + mt * 16;
            int b = m >> 12, t = m & 4095;
            #pragma unroll
            for (int nt = 0; nt < 4; ++nt) {
                int n = n0 + nt * 16;
                int h = n >> 6, d = n & 63;
                bf16x4 pk;
                #pragma unroll
                for (int r = 0; r < 4; ++r) pk[r] = (bf16)acc[mt][nt][r];
                *(bf16x4*)(dst + (((size_t)b * H_ + h) * 64 + d) * T_ + t) = pk;
            }
        }
    }
}

// ---------------- output projection GEMM (round-9: 3-buf counted-vmcnt) -----
__global__ __launch_bounds__(256) void gemm_out(const bf16* __restrict__ ctx,
                                                const bf16* __restrict__ wob,
                                                float* __restrict__ out) {
    int mbase = blockIdx.x * 128;
    int nbase = blockIdx.y * 128;
    __shared__ bf16 As[3][128][32];
    __shared__ bf16 Bs[3][128][32];
    int tid  = threadIdx.x;
    int wave = tid >> 6, lane = tid & 63;
    int wm = (wave >> 1) * 64, wn = (wave & 1) * 64;
    int lr = lane & 15, lg = lane >> 4;
    int srow0 = tid >> 2, scol0 = tid & 3;
    int srow1 = (tid + 256) >> 2, scol1 = (tid + 256) & 3;
    const bf16* xa0 = ctx + (size_t)(mbase + srow0) * C_ + scol0 * 8;
    const bf16* xa1 = ctx + (size_t)(mbase + srow1) * C_ + scol1 * 8;
    const bf16* wa0 = wob + (size_t)(nbase + srow0) * C_ + scol0 * 8;
    const bf16* wa1 = wob + (size_t)(nbase + srow1) * C_ + scol1 * 8;
#define GSTAGE(kb_, cb_) do { \
        gl_lds16(xa0 + (kb_), &As[cb_][srow0][scol0 * 8]); \
        gl_lds16(xa1 + (kb_), &As[cb_][srow1][scol1 * 8]); \
        gl_lds16(wa0 + (kb_), &Bs[cb_][srow0][scol0 * 8]); \
        gl_lds16(wa1 + (kb_), &Bs[cb_][srow1][scol1 * 8]); \
    } while (0)
    f32x4 acc[4][4] = {};
    GSTAGE(0, 0);
    GSTAGE(32, 1);
    asm volatile("s_waitcnt vmcnt(4)" ::: "memory");
    __builtin_amdgcn_s_barrier();
    int cur = 0, stg = 2;
    for (int t = 0; t < 24; ++t) {
        if (t + 2 < 24) GSTAGE((t + 2) * 32, stg);
        bf16x8 af[4], bfr[4];
        #pragma unroll
        for (int mt = 0; mt < 4; ++mt) af[mt]  = *(const bf16x8*)(&As[cur][wm + mt*16 + lr][lg*8]);
        #pragma unroll
        for (int nt = 0; nt < 4; ++nt) bfr[nt] = *(const bf16x8*)(&Bs[cur][wn + nt*16 + lr][lg*8]);
        #pragma unroll
        for (int mt = 0; mt < 4; ++mt)
            #pragma unroll
            for (int nt = 0; nt < 4; ++nt)
                acc[mt][nt] = __builtin_amdgcn_mfma_f32_16x16x32_bf16(af[mt], bfr[nt], acc[mt][nt], 0, 0, 0);
        if (t + 2 < 24) {
            asm volatile("s_waitcnt vmcnt(4)" ::: "memory");
            __builtin_amdgcn_s_barrier();
        } else if (t + 1 < 24) {
            asm volatile("s_waitcnt vmcnt(0)" ::: "memory");
            __builtin_amdgcn_s_barrier();
        }
        cur = (cur == 2) ? 0 : cur + 1;
        stg = (stg == 2) ? 0 : stg + 1;
    }
#undef GSTAGE
    int m0 = mbase + wm + (lg << 2);
    int n0 = nbase + wn + lr;
    #pragma unroll
    for (int mt = 0; mt < 4; ++mt)
        #pragma unroll
        for (int nt = 0; nt < 4; ++nt)
            #pragma unroll
            for (int r = 0; r < 4; ++r)
                out[(size_t)(m0 + mt * 16 + r) * C_ + n0 + nt * 16] = acc[mt][nt][r];
}

// ---------------- causal flash attention (round-7 version, unchanged) -------
// 90 µs, bank conflicts 0, DMA-staged dbuf, fixed-max exp2 softmax, in-reg P.
__device__ __forceinline__ void attn_store(const f32x4 (&o)[4], float l, bf16* __restrict__ ctx,
                                           int b, int qrow, int h, int lg) {
    float inv = 1.0f / l;
    #pragma unroll
    for (int dt = 0; dt < 4; ++dt) {
        bf16x4 pk;
        #pragma unroll
        for (int r = 0; r < 4; ++r) pk[r] = (bf16)(o[dt][r] * inv);
        *(bf16x4*)(ctx + ((size_t)b * T_ + qrow) * C_ + h * 64 + dt * 16 + lg * 4) = pk;
    }
}

__global__ __launch_bounds__(256) void attn(const bf16* __restrict__ q,
                                            const bf16* __restrict__ k,
                                            const bf16* __restrict__ vt,
                                            bf16* __restrict__ ctx) {
    int idx = blockIdx.x;          // 0..1535
    int qt = 63 - idx / 24;        // globally sorted descending work
    int bh = idx % 24;
    int b = bh / H_, h = bh % H_;
    int tid = threadIdx.x;
    int wave = tid >> 6, lane = tid & 63;
    int lr = lane & 15, lg = lane >> 4;

    __shared__ bf16 Ks[2][64][64]; // double-buffered K tile (keys x d), swizzled
    __shared__ bf16 Vs[2][64][64]; // double-buffered V^T tile (d x keys), swizzled

    const bf16* qp = q  + (size_t)bh * T_ * 64;
    const bf16* kp = k  + (size_t)bh * T_ * 64;
    const bf16* vp = vt + (size_t)bh * 64 * (size_t)T_;

    // staging: thread tid owns LDS 16B chunk (row r0, chunk c0) = linear tid*16;
    // source column pre-swizzled so LDS[row][j] = G[row][j ^ (row&7)]
    int r0 = tid >> 3, c0 = tid & 7;
    int cs = (c0 ^ (r0 & 7)) * 8;                    // swizzled source col (elems)
    const bf16* kstg = kp + (size_t)r0 * 64 + cs;
    const bf16* vstg = vp + (size_t)r0 * T_ + cs;

#define STAGE(kb_, cb_) do { \
        const bf16* ks_ = kstg + (size_t)(kb_) * 64 * 64; \
        const bf16* vs_ = vstg + (size_t)(kb_) * 64; \
        gl_lds16(ks_,                   &Ks[cb_][r0][c0 * 8]); \
        gl_lds16(ks_ + 32 * 64,         &Ks[cb_][32 + r0][c0 * 8]); \
        gl_lds16(vs_,                   &Vs[cb_][r0][c0 * 8]); \
        gl_lds16(vs_ + (size_t)32 * T_, &Vs[cb_][32 + r0][c0 * 8]); \
    } while (0)

    const float NEGINF = -__builtin_inff();

    int qb = qt * 64 + wave * 16;
    int n  = qt + 1;
    int qrow = qb + lr;

    // read-side swizzled chunk offsets (loop-invariant per lane)
    int sw = lr & 7;
    int col0 = (lg ^ sw) * 8;           // chunk c2=0: (0*4+lg) ^ (row&7)
    int col1 = ((4 | lg) ^ sw) * 8;     // chunk c2=1: (1*4+lg) ^ (row&7)

    bf16x8 qf[2];
    #pragma unroll
    for (int c = 0; c < 2; ++c)
        qf[c] = *(const bf16x8*)(qp + (size_t)(qb + lr) * 64 + c * 32 + lg * 8);

    f32x4 o[4] = {};
    float lsum = 0.f;
    const f32x4 fz = {};           // loop-invariant zero C operand

    STAGE(0, 0);
    __syncthreads();               // drain DMA for tile 0
    int cur = 0;

    for (int kb = 0; kb < n; ++kb) {
        int kv = kb * 64;
        if (kb + 1 < n) STAGE(kb + 1, cur ^ 1);   // DMA overlaps compute below

        // S^T = K Q^T : rows = keys (A-frag from LDS), cols = q (lane lr)
        f32x4 s[4];
        __builtin_amdgcn_s_setprio(1);
        #pragma unroll
        for (int nt = 0; nt < 4; ++nt) {
            bf16x8 kf0 = *(const bf16x8*)(&Ks[cur][nt * 16 + lr][col0]);
            s[nt] = __builtin_amdgcn_mfma_f32_16x16x32_bf16(kf0, qf[0], fz, 0, 0, 0);
        }
        #pragma unroll
        for (int nt = 0; nt < 4; ++nt) {
            bf16x8 kf1 = *(const bf16x8*)(&Ks[cur][nt * 16 + lr][col1]);
            s[nt] = __builtin_amdgcn_mfma_f32_16x16x32_bf16(kf1, qf[1], s[nt], 0, 0, 0);
        }
        __builtin_amdgcn_s_setprio(0);
        // causal mask (diagonal tile only; Q pre-scaled by 0.125*log2e)
        if (kb == qt) {
            #pragma unroll
            for (int nt = 0; nt < 4; ++nt)
                #pragma unroll
                for (int r = 0; r < 4; ++r) {
                    int key = kv + nt * 16 + lg * 4 + r;
                    s[nt][r] = (key > qrow) ? NEGINF : s[nt][r];
                }
        }
        // fixed-max softmax: p = exp2(s), no per-iter reduction
        #pragma unroll
        for (int nt = 0; nt < 4; ++nt) {
            #pragma unroll
            for (int r = 0; r < 4; ++r)
                s[nt][r] = __builtin_amdgcn_exp2f(s[nt][r]);
            lsum += (s[nt][0] + s[nt][1]) + (s[nt][2] + s[nt][3]);
        }
        // P: S-frag -> PV B-frag entirely in registers (no LDS round-trip)
        unsigned int dpk[8];
        #pragma unroll
        for (int nt = 0; nt < 4; ++nt) {
            dpk[2*nt]   = cvtpk(s[nt][0], s[nt][1]);
            dpk[2*nt+1] = cvtpk(s[nt][2], s[nt][3]);
        }
        unsigned int pw[2][4];
        #pragma unroll
        for (int c2 = 0; c2 < 2; ++c2)
            #pragma unroll
            for (int pr = 0; pr < 2; ++pr) {
                unsigned int x = dpk[4*c2 + pr], y = dpk[4*c2 + 2 + pr];
                pswap32_16(x, y);
                pw[c2][pr] = x;      // word pr   (keys c2*32+lg*8 + {2pr,2pr+1})
                pw[c2][2+pr] = y;    // word pr+2 (keys c2*32+lg*8 + {4+2pr,5+2pr})
            }
        // O^T += V^T P^T : A = V^T frag from LDS (swizzled cols), B = P frag
        __builtin_amdgcn_s_setprio(1);
        #pragma unroll
        for (int c2 = 0; c2 < 2; ++c2) {
            u32x4 pt;
            pt[0] = pw[c2][0]; pt[1] = pw[c2][1]; pt[2] = pw[c2][2]; pt[3] = pw[c2][3];
            bf16x8 pf = __builtin_bit_cast(bf16x8, pt);
            int vcol = c2 ? col1 : col0;
            #pragma unroll
            for (int dt = 0; dt < 4; ++dt) {
                bf16x8 vfr = *(const bf16x8*)(&Vs[cur][dt * 16 + lr][vcol]);
                o[dt] = __builtin_amdgcn_mfma_f32_16x16x32_bf16(vfr, pf, o[dt], 0, 0, 0);
            }
        }
        __builtin_amdgcn_s_setprio(0);

        __syncthreads();           // drains next-tile DMA + all waves done with cur
        cur ^= 1;
    }
#undef STAGE

    // single cross-lane reduction for l (row lr spread across 4 lg groups)
    float l = lsum;
    l += __shfl_xor(l, 16, 64);
    l += __shfl_xor(l, 32, 64);
    attn_store(o, l, ctx, b, qrow, h, lg);
}

// ---------------- launch ----------------
extern "C" void kernel_launch(void* const* d_in, const int* in_sizes, int n_in,
                              void* d_out, int out_size, void* d_ws, size_t ws_size,
                              hipStream_t stream) {
    const float* x  = (const float*)d_in[0];
    const float* wq = (const float*)d_in[1];
    const float* wk = (const float*)d_in[2];
    const float* wv = (const float*)d_in[3];
    const float* wo = (const float*)d_in[4];
    float* out = (float*)d_out;

    char* ws = (char*)d_ws;
    const size_t SZ_XB = (size_t)MTOT * C_ * sizeof(bf16);
    const size_t SZ_W  = (size_t)C_ * C_ * sizeof(bf16);
    bf16* xb  = (bf16*)(ws);
    bf16* wqb = (bf16*)(ws + SZ_XB);
    bf16* wkb = (bf16*)(ws + SZ_XB + SZ_W);
    bf16* wvb = (bf16*)(ws + SZ_XB + 2 * SZ_W);
    bf16* wob = (bf16*)(ws + SZ_XB + 3 * SZ_W);
    bf16* qb  = (bf16*)(ws + SZ_XB + 4 * SZ_W);
    bf16* kb  = (bf16*)(ws + 2 * SZ_XB + 4 * SZ_W);
    bf16* vtb = (bf16*)(ws + 3 * SZ_XB + 4 * SZ_W);
    bf16* ctb = (bf16*)(ws + 4 * SZ_XB + 4 * SZ_W);

    cvt_bf16<<<3072, 256, 0, stream>>>(x, xb, MTOT * C_ / 8);
    cvt_bf16_w4<<<dim3(288, 4), 256, 0, stream>>>(wq, wk, wv, wo, wqb, wkb, wvb, wob);

    gemm_qkv<<<dim3(MTOT / 128, C_ / 128, 3), 256, 0, stream>>>(xb, wqb, wkb, wvb, qb, kb, vtb);
    attn<<<1536, 256, 0, stream>>>(qb, kb, vtb, ctb);
    gemm_out<<<dim3(MTOT / 128, C_ / 128), 256, 0, stream>>>(ctb, wob, out);
}

// Round 10
// 236.739 us; speedup vs baseline: 1.0636x; 1.0636x over previous
//
#include <hip/hip_runtime.h>
#include <hip/hip_bf16.h>

#define B_  2
#define T_  4096
#define C_  768
#define H_  12
#define D_  64
#define MTOT (B_*T_)   // 8192

typedef __bf16 bf16;
typedef __bf16 bf16x8 __attribute__((ext_vector_type(8)));
typedef __bf16 bf16x4 __attribute__((ext_vector_type(4)));
typedef float  f32x4  __attribute__((ext_vector_type(4)));
typedef unsigned int u32x4 __attribute__((ext_vector_type(4)));

// async global->LDS, 16B per lane; LDS dest must be wave-uniform base + lane*16
__device__ __forceinline__ void gl_lds16(const bf16* g, bf16* l) {
    __builtin_amdgcn_global_load_lds(
        (const __attribute__((address_space(1))) void*)g,
        (__attribute__((address_space(3))) void*)l, 16, 0, 0);
}

// ---- P redistribution via permlane-swap BUILTINS ----
__device__ __forceinline__ void pswap32_16(unsigned int& x, unsigned int& y) {
    auto r1 = __builtin_amdgcn_permlane32_swap(x, y, false, false);
    auto r2 = __builtin_amdgcn_permlane16_swap(r1[0], r1[1], false, false);
    x = r2[0]; y = r2[1];
}
__device__ __forceinline__ unsigned int cvtpk(float lo, float hi) {
    unsigned int r;
    asm("v_cvt_pk_bf16_f32 %0, %1, %2" : "=v"(r) : "v"(lo), "v"(hi));
    return r;
}

// ---------------- fp32 -> bf16 convert ----------------
__global__ __launch_bounds__(256) void cvt_bf16(const float* __restrict__ src,
                                                bf16* __restrict__ dst, int n8) {
    int i = blockIdx.x * 256 + threadIdx.x;
    if (i >= n8) return;
    const float4* s4 = (const float4*)src;
    float4 a = s4[2*(size_t)i], b = s4[2*(size_t)i+1];
    bf16x8 o;
    o[0]=(bf16)a.x; o[1]=(bf16)a.y; o[2]=(bf16)a.z; o[3]=(bf16)a.w;
    o[4]=(bf16)b.x; o[5]=(bf16)b.y; o[6]=(bf16)b.z; o[7]=(bf16)b.w;
    *(bf16x8*)(dst + 8*(size_t)i) = o;
}

__global__ __launch_bounds__(256) void cvt_bf16_w4(const float* __restrict__ w0,
                                                   const float* __restrict__ w1,
                                                   const float* __restrict__ w2,
                                                   const float* __restrict__ w3,
                                                   bf16* __restrict__ d0,
                                                   bf16* __restrict__ d1,
                                                   bf16* __restrict__ d2,
                                                   bf16* __restrict__ d3) {
    int z = blockIdx.y;
    const float* src = (z==0)?w0:(z==1)?w1:(z==2)?w2:w3;
    bf16* dst = (z==0)?d0:(z==1)?d1:(z==2)?d2:d3;
    int i = blockIdx.x * 256 + threadIdx.x;
    const float4* s4 = (const float4*)src;
    float4 a = s4[2*(size_t)i], b = s4[2*(size_t)i+1];
    bf16x8 o;
    o[0]=(bf16)a.x; o[1]=(bf16)a.y; o[2]=(bf16)a.z; o[3]=(bf16)a.w;
    o[4]=(bf16)b.x; o[5]=(bf16)b.y; o[6]=(bf16)b.z; o[7]=(bf16)b.w;
    *(bf16x8*)(dst + 8*(size_t)i) = o;
}

// ---------------- QKV projection GEMM (round-10: round-8 structure) ---------
// Round-9 post-mortem: 3-buf counted-vmcnt cut occupancy 5->3 blocks/CU and
// cost +23 µs — this GEMM is TLP-bound, not pipeline-depth-bound. Revert to
// the round-8 loop (2-buf 32KB, STAGE(next) before compute, __syncthreads).
// Keep round-9's packed z<2 epilogue (operand-swapped MFMA: regs walk the
// feature dim -> bf16x4 stores; refcheck-verified, strictly fewer insts).
// z=0 -> Q (pre-scaled by 0.125*log2e) in (B,H,T,D); z=1 -> K; z=2 -> V^T.
__global__ __launch_bounds__(256) void gemm_qkv(const bf16* __restrict__ xb,
                                                const bf16* __restrict__ wqb,
                                                const bf16* __restrict__ wkb,
                                                const bf16* __restrict__ wvb,
                                                bf16* __restrict__ qo,
                                                bf16* __restrict__ ko,
                                                bf16* __restrict__ vto) {
    int z = blockIdx.z;
    const bf16* w = (z == 0) ? wqb : (z == 1) ? wkb : wvb;
    bf16* dst = (z == 0) ? qo : (z == 1) ? ko : vto;
    int mbase = blockIdx.x * 128;
    int nbase = blockIdx.y * 128;
    __shared__ bf16 As[2][128][32];   // UNPADDED: global_load_lds lane-contiguous
    __shared__ bf16 Bs[2][128][32];
    int tid  = threadIdx.x;
    int wave = tid >> 6, lane = tid & 63;
    int wm = (wave >> 1) * 64, wn = (wave & 1) * 64;
    int lr = lane & 15, lg = lane >> 4;
    int srow0 = tid >> 2, scol0 = tid & 3;
    int srow1 = (tid + 256) >> 2, scol1 = (tid + 256) & 3;
    const bf16* xa0 = xb + (size_t)(mbase + srow0) * C_ + scol0 * 8;
    const bf16* xa1 = xb + (size_t)(mbase + srow1) * C_ + scol1 * 8;
    const bf16* wa0 = w  + (size_t)(nbase + srow0) * C_ + scol0 * 8;
    const bf16* wa1 = w  + (size_t)(nbase + srow1) * C_ + scol1 * 8;
#define GSTAGE(kb_, cb_) do { \
        gl_lds16(xa0 + (kb_), &As[cb_][srow0][scol0 * 8]); \
        gl_lds16(xa1 + (kb_), &As[cb_][srow1][scol1 * 8]); \
        gl_lds16(wa0 + (kb_), &Bs[cb_][srow0][scol0 * 8]); \
        gl_lds16(wa1 + (kb_), &Bs[cb_][srow1][scol1 * 8]); \
    } while (0)
    f32x4 acc[4][4] = {};
    GSTAGE(0, 0);
    __syncthreads();               // drain DMA for tile 0
    int cur = 0;
    for (int kb = 0; kb < C_; kb += 32) {
        if (kb + 32 < C_) GSTAGE(kb + 32, cur ^ 1);   // DMA overlaps compute
        bf16x8 af[4], bfr[4];
        #pragma unroll
        for (int mt = 0; mt < 4; ++mt) af[mt]  = *(const bf16x8*)(&As[cur][wm + mt*16 + lr][lg*8]);
        #pragma unroll
        for (int nt = 0; nt < 4; ++nt) bfr[nt] = *(const bf16x8*)(&Bs[cur][wn + nt*16 + lr][lg*8]);
        if (z < 2) {            // transposed acc: regs -> n (feature), lane -> m
            #pragma unroll
            for (int mt = 0; mt < 4; ++mt)
                #pragma unroll
                for (int nt = 0; nt < 4; ++nt)
                    acc[mt][nt] = __builtin_amdgcn_mfma_f32_16x16x32_bf16(bfr[nt], af[mt], acc[mt][nt], 0, 0, 0);
        } else {                // normal acc: regs -> m, lane -> n
            #pragma unroll
            for (int mt = 0; mt < 4; ++mt)
                #pragma unroll
                for (int nt = 0; nt < 4; ++nt)
                    acc[mt][nt] = __builtin_amdgcn_mfma_f32_16x16x32_bf16(af[mt], bfr[nt], acc[mt][nt], 0, 0, 0);
        }
        __syncthreads();           // next-tile DMA landed + all reads of cur done
        cur ^= 1;
    }
#undef GSTAGE
    float sc = (z == 0) ? 0.18033688011112042f : 1.0f;  // 0.125*log2(e) folded into Q
    if (z < 2) {
        // transposed: m = token from lane, n = feature from regs -> packed d-stores
        int m0 = mbase + wm + lr;
        int n0 = nbase + wn + (lg << 2);
        #pragma unroll
        for (int mt = 0; mt < 4; ++mt) {
            int m = m0 + mt * 16;
            int b = m >> 12, t = m & 4095;
            #pragma unroll
            for (int nt = 0; nt < 4; ++nt) {
                int n = n0 + nt * 16;
                int h = n >> 6, d = n & 63;
                bf16x4 pk;
                #pragma unroll
                for (int r = 0; r < 4; ++r) pk[r] = (bf16)(acc[mt][nt][r] * sc);
                *(bf16x4*)(dst + (((size_t)b * H_ + h) * T_ + t) * 64 + d) = pk;
            }
        }
    } else {
        int m0 = mbase + wm + (lg << 2);
        int n0 = nbase + wn + lr;
        #pragma unroll
        for (int mt = 0; mt < 4; ++mt) {
            int m = m0 + mt * 16;
            int b = m >> 12, t = m & 4095;
            #pragma unroll
            for (int nt = 0; nt < 4; ++nt) {
                int n = n0 + nt * 16;
                int h = n >> 6, d = n & 63;
                bf16x4 pk;
                #pragma unroll
                for (int r = 0; r < 4; ++r) pk[r] = (bf16)acc[mt][nt][r];
                *(bf16x4*)(dst + (((size_t)b * H_ + h) * 64 + d) * T_ + t) = pk;
            }
        }
    }
}

// ---------------- output projection GEMM (round-8 structure) ----------------
__global__ __launch_bounds__(256) void gemm_out(const bf16* __restrict__ ctx,
                                                const bf16* __restrict__ wob,
                                                float* __restrict__ out) {
    int mbase = blockIdx.x * 128;
    int nbase = blockIdx.y * 128;
    __shared__ bf16 As[2][128][32];
    __shared__ bf16 Bs[2][128][32];
    int tid  = threadIdx.x;
    int wave = tid >> 6, lane = tid & 63;
    int wm = (wave >> 1) * 64, wn = (wave & 1) * 64;
    int lr = lane & 15, lg = lane >> 4;
    int srow0 = tid >> 2, scol0 = tid & 3;
    int srow1 = (tid + 256) >> 2, scol1 = (tid + 256) & 3;
    const bf16* xa0 = ctx + (size_t)(mbase + srow0) * C_ + scol0 * 8;
    const bf16* xa1 = ctx + (size_t)(mbase + srow1) * C_ + scol1 * 8;
    const bf16* wa0 = wob + (size_t)(nbase + srow0) * C_ + scol0 * 8;
    const bf16* wa1 = wob + (size_t)(nbase + srow1) * C_ + scol1 * 8;
#define GSTAGE(kb_, cb_) do { \
        gl_lds16(xa0 + (kb_), &As[cb_][srow0][scol0 * 8]); \
        gl_lds16(xa1 + (kb_), &As[cb_][srow1][scol1 * 8]); \
        gl_lds16(wa0 + (kb_), &Bs[cb_][srow0][scol0 * 8]); \
        gl_lds16(wa1 + (kb_), &Bs[cb_][srow1][scol1 * 8]); \
    } while (0)
    f32x4 acc[4][4] = {};
    GSTAGE(0, 0);
    __syncthreads();
    int cur = 0;
    for (int kb = 0; kb < C_; kb += 32) {
        if (kb + 32 < C_) GSTAGE(kb + 32, cur ^ 1);
        bf16x8 af[4], bfr[4];
        #pragma unroll
        for (int mt = 0; mt < 4; ++mt) af[mt]  = *(const bf16x8*)(&As[cur][wm + mt*16 + lr][lg*8]);
        #pragma unroll
        for (int nt = 0; nt < 4; ++nt) bfr[nt] = *(const bf16x8*)(&Bs[cur][wn + nt*16 + lr][lg*8]);
        #pragma unroll
        for (int mt = 0; mt < 4; ++mt)
            #pragma unroll
            for (int nt = 0; nt < 4; ++nt)
                acc[mt][nt] = __builtin_amdgcn_mfma_f32_16x16x32_bf16(af[mt], bfr[nt], acc[mt][nt], 0, 0, 0);
        __syncthreads();
        cur ^= 1;
    }
#undef GSTAGE
    int m0 = mbase + wm + (lg << 2);
    int n0 = nbase + wn + lr;
    #pragma unroll
    for (int mt = 0; mt < 4; ++mt)
        #pragma unroll
        for (int nt = 0; nt < 4; ++nt)
            #pragma unroll
            for (int r = 0; r < 4; ++r)
                out[(size_t)(m0 + mt * 16 + r) * C_ + n0 + nt * 16] = acc[mt][nt][r];
}

// ---------------- causal flash attention (round-10: l-sum on MFMA pipe) -----
// VALU is attn's busiest pipe (61% vs MFMA 24%). The PV B-frag pf already
// holds P[32 keys][16 q]; one MFMA with an all-ones A-frag computes
// sum_k P[k][q] for every q — the hardware does the cross-lane k-reduction.
// 2 MFMAs/iter (idle pipe) replace 16 v_add_f32/iter AND the final 2-shfl
// reduction (every lane holds the full l of its q-column; all output rows
// identical by A=ones). l is now the sum of the SAME bf16-rounded P used in
// PV (masked keys: exp2(-inf)=0). Rest identical to round-7 (90 µs, 0 confl).
__device__ __forceinline__ void attn_store(const f32x4 (&o)[4], float l, bf16* __restrict__ ctx,
                                           int b, int qrow, int h, int lg) {
    float inv = 1.0f / l;
    #pragma unroll
    for (int dt = 0; dt < 4; ++dt) {
        bf16x4 pk;
        #pragma unroll
        for (int r = 0; r < 4; ++r) pk[r] = (bf16)(o[dt][r] * inv);
        *(bf16x4*)(ctx + ((size_t)b * T_ + qrow) * C_ + h * 64 + dt * 16 + lg * 4) = pk;
    }
}

__global__ __launch_bounds__(256) void attn(const bf16* __restrict__ q,
                                            const bf16* __restrict__ k,
                                            const bf16* __restrict__ vt,
                                            bf16* __restrict__ ctx) {
    int idx = blockIdx.x;          // 0..1535
    int qt = 63 - idx / 24;        // globally sorted descending work
    int bh = idx % 24;
    int b = bh / H_, h = bh % H_;
    int tid = threadIdx.x;
    int wave = tid >> 6, lane = tid & 63;
    int lr = lane & 15, lg = lane >> 4;

    __shared__ bf16 Ks[2][64][64]; // double-buffered K tile (keys x d), swizzled
    __shared__ bf16 Vs[2][64][64]; // double-buffered V^T tile (d x keys), swizzled

    const bf16* qp = q  + (size_t)bh * T_ * 64;
    const bf16* kp = k  + (size_t)bh * T_ * 64;
    const bf16* vp = vt + (size_t)bh * 64 * (size_t)T_;

    // staging: thread tid owns LDS 16B chunk (row r0, chunk c0) = linear tid*16;
    // source column pre-swizzled so LDS[row][j] = G[row][j ^ (row&7)]
    int r0 = tid >> 3, c0 = tid & 7;
    int cs = (c0 ^ (r0 & 7)) * 8;                    // swizzled source col (elems)
    const bf16* kstg = kp + (size_t)r0 * 64 + cs;
    const bf16* vstg = vp + (size_t)r0 * T_ + cs;

#define STAGE(kb_, cb_) do { \
        const bf16* ks_ = kstg + (size_t)(kb_) * 64 * 64; \
        const bf16* vs_ = vstg + (size_t)(kb_) * 64; \
        gl_lds16(ks_,                   &Ks[cb_][r0][c0 * 8]); \
        gl_lds16(ks_ + 32 * 64,         &Ks[cb_][32 + r0][c0 * 8]); \
        gl_lds16(vs_,                   &Vs[cb_][r0][c0 * 8]); \
        gl_lds16(vs_ + (size_t)32 * T_, &Vs[cb_][32 + r0][c0 * 8]); \
    } while (0)

    const float NEGINF = -__builtin_inff();

    int qb = qt * 64 + wave * 16;
    int n  = qt + 1;
    int qrow = qb + lr;

    // read-side swizzled chunk offsets (loop-invariant per lane)
    int sw = lr & 7;
    int col0 = (lg ^ sw) * 8;           // chunk c2=0: (0*4+lg) ^ (row&7)
    int col1 = ((4 | lg) ^ sw) * 8;     // chunk c2=1: (1*4+lg) ^ (row&7)

    bf16x8 qf[2];
    #pragma unroll
    for (int c = 0; c < 2; ++c)
        qf[c] = *(const bf16x8*)(qp + (size_t)(qb + lr) * 64 + c * 32 + lg * 8);

    // all-ones A-frag for the l-sum MFMA (bf16 1.0 = 0x3F80)
    u32x4 onep;
    onep[0] = 0x3F803F80u; onep[1] = 0x3F803F80u; onep[2] = 0x3F803F80u; onep[3] = 0x3F803F80u;
    bf16x8 ones = __builtin_bit_cast(bf16x8, onep);

    f32x4 o[4] = {};
    f32x4 lacc = {};
    const f32x4 fz = {};           // loop-invariant zero C operand

    STAGE(0, 0);
    __syncthreads();               // drain DMA for tile 0
    int cur = 0;

    for (int kb = 0; kb < n; ++kb) {
        int kv = kb * 64;
        if (kb + 1 < n) STAGE(kb + 1, cur ^ 1);   // DMA overlaps compute below

        // S^T = K Q^T : rows = keys (A-frag from LDS), cols = q (lane lr)
        f32x4 s[4];
        __builtin_amdgcn_s_setprio(1);
        #pragma unroll
        for (int nt = 0; nt < 4; ++nt) {
            bf16x8 kf0 = *(const bf16x8*)(&Ks[cur][nt * 16 + lr][col0]);
            s[nt] = __builtin_amdgcn_mfma_f32_16x16x32_bf16(kf0, qf[0], fz, 0, 0, 0);
        }
        #pragma unroll
        for (int nt = 0; nt < 4; ++nt) {
            bf16x8 kf1 = *(const bf16x8*)(&Ks[cur][nt * 16 + lr][col1]);
            s[nt] = __builtin_amdgcn_mfma_f32_16x16x32_bf16(kf1, qf[1], s[nt], 0, 0, 0);
        }
        __builtin_amdgcn_s_setprio(0);
        // causal mask (diagonal tile only; Q pre-scaled by 0.125*log2e)
        if (kb == qt) {
            #pragma unroll
            for (int nt = 0; nt < 4; ++nt)
                #pragma unroll
                for (int r = 0; r < 4; ++r) {
                    int key = kv + nt * 16 + lg * 4 + r;
                    s[nt][r] = (key > qrow) ? NEGINF : s[nt][r];
                }
        }
        // fixed-max softmax: p = exp2(s); l accumulated on the MFMA pipe below
        #pragma unroll
        for (int nt = 0; nt < 4; ++nt)
            #pragma unroll
            for (int r = 0; r < 4; ++r)
                s[nt][r] = __builtin_amdgcn_exp2f(s[nt][r]);
        // P: S-frag -> PV B-frag entirely in registers (no LDS round-trip)
        unsigned int dpk[8];
        #pragma unroll
        for (int nt = 0; nt < 4; ++nt) {
            dpk[2*nt]   = cvtpk(s[nt][0], s[nt][1]);
            dpk[2*nt+1] = cvtpk(s[nt][2], s[nt][3]);
        }
        unsigned int pw[2][4];
        #pragma unroll
        for (int c2 = 0; c2 < 2; ++c2)
            #pragma unroll
            for (int pr = 0; pr < 2; ++pr) {
                unsigned int x = dpk[4*c2 + pr], y = dpk[4*c2 + 2 + pr];
                pswap32_16(x, y);
                pw[c2][pr] = x;      // word pr   (keys c2*32+lg*8 + {2pr,2pr+1})
                pw[c2][2+pr] = y;    // word pr+2 (keys c2*32+lg*8 + {4+2pr,5+2pr})
            }
        // O^T += V^T P^T ; l += 1^T P  (A=ones row-sums P on the MFMA pipe)
        __builtin_amdgcn_s_setprio(1);
        #pragma unroll
        for (int c2 = 0; c2 < 2; ++c2) {
            u32x4 pt;
            pt[0] = pw[c2][0]; pt[1] = pw[c2][1]; pt[2] = pw[c2][2]; pt[3] = pw[c2][3];
            bf16x8 pf = __builtin_bit_cast(bf16x8, pt);
            int vcol = c2 ? col1 : col0;
            #pragma unroll
            for (int dt = 0; dt < 4; ++dt) {
                bf16x8 vfr = *(const bf16x8*)(&Vs[cur][dt * 16 + lr][vcol]);
                o[dt] = __builtin_amdgcn_mfma_f32_16x16x32_bf16(vfr, pf, o[dt], 0, 0, 0);
            }
            lacc = __builtin_amdgcn_mfma_f32_16x16x32_bf16(ones, pf, lacc, 0, 0, 0);
        }
        __builtin_amdgcn_s_setprio(0);

        __syncthreads();           // drains next-tile DMA + all waves done with cur
        cur ^= 1;
    }
#undef STAGE

    // lacc[r] = full sum over ALL keys of P[.][lr] (identical across rows/lg)
    attn_store(o, lacc[0], ctx, b, qrow, h, lg);
}

// ---------------- launch ----------------
extern "C" void kernel_launch(void* const* d_in, const int* in_sizes, int n_in,
                              void* d_out, int out_size, void* d_ws, size_t ws_size,
                              hipStream_t stream) {
    const float* x  = (const float*)d_in[0];
    const float* wq = (const float*)d_in[1];
    const float* wk = (const float*)d_in[2];
    const float* wv = (const float*)d_in[3];
    const float* wo = (const float*)d_in[4];
    float* out = (float*)d_out;

    char* ws = (char*)d_ws;
    const size_t SZ_XB = (size_t)MTOT * C_ * sizeof(bf16);
    const size_t SZ_W  = (size_t)C_ * C_ * sizeof(bf16);
    bf16* xb  = (bf16*)(ws);
    bf16* wqb = (bf16*)(ws + SZ_XB);
    bf16* wkb = (bf16*)(ws + SZ_XB + SZ_W);
    bf16* wvb = (bf16*)(ws + SZ_XB + 2 * SZ_W);
    bf16* wob = (bf16*)(ws + SZ_XB + 3 * SZ_W);
    bf16* qb  = (bf16*)(ws + SZ_XB + 4 * SZ_W);
    bf16* kb  = (bf16*)(ws + 2 * SZ_XB + 4 * SZ_W);
    bf16* vtb = (bf16*)(ws + 3 * SZ_XB + 4 * SZ_W);
    bf16* ctb = (bf16*)(ws + 4 * SZ_XB + 4 * SZ_W);

    cvt_bf16<<<3072, 256, 0, stream>>>(x, xb, MTOT * C_ / 8);
    cvt_bf16_w4<<<dim3(288, 4), 256, 0, stream>>>(wq, wk, wv, wo, wqb, wkb, wvb, wob);

    gemm_qkv<<<dim3(MTOT / 128, C_ / 128, 3), 256, 0, stream>>>(xb, wqb, wkb, wvb, qb, kb, vtb);
    attn<<<1536, 256, 0, stream>>>(qb, kb, vtb, ctb);
    gemm_out<<<dim3(MTOT / 128, C_ / 128), 256, 0, stream>>>(ctb, wob, out);
}

// Round 11
// 227.611 us; speedup vs baseline: 1.1063x; 1.0401x over previous
//
#include <hip/hip_runtime.h>
#include <hip/hip_bf16.h>

#define B_  2
#define T_  4096
#define C_  768
#define H_  12
#define D_  64
#define MTOT (B_*T_)   // 8192

typedef __bf16 bf16;
typedef __bf16 bf16x8 __attribute__((ext_vector_type(8)));
typedef __bf16 bf16x4 __attribute__((ext_vector_type(4)));
typedef float  f32x4  __attribute__((ext_vector_type(4)));
typedef unsigned int u32x4 __attribute__((ext_vector_type(4)));

// async global->LDS, 16B per lane; LDS dest must be wave-uniform base + lane*16
__device__ __forceinline__ void gl_lds16(const bf16* g, bf16* l) {
    __builtin_amdgcn_global_load_lds(
        (const __attribute__((address_space(1))) void*)g,
        (__attribute__((address_space(3))) void*)l, 16, 0, 0);
}

// ---- P redistribution via permlane-swap BUILTINS ----
__device__ __forceinline__ void pswap32_16(unsigned int& x, unsigned int& y) {
    auto r1 = __builtin_amdgcn_permlane32_swap(x, y, false, false);
    auto r2 = __builtin_amdgcn_permlane16_swap(r1[0], r1[1], false, false);
    x = r2[0]; y = r2[1];
}
__device__ __forceinline__ unsigned int cvtpk(float lo, float hi) {
    unsigned int r;
    asm("v_cvt_pk_bf16_f32 %0, %1, %2" : "=v"(r) : "v"(lo), "v"(hi));
    return r;
}

// ---------------- fp32 -> bf16 convert ----------------
__global__ __launch_bounds__(256) void cvt_bf16(const float* __restrict__ src,
                                                bf16* __restrict__ dst, int n8) {
    int i = blockIdx.x * 256 + threadIdx.x;
    if (i >= n8) return;
    const float4* s4 = (const float4*)src;
    float4 a = s4[2*(size_t)i], b = s4[2*(size_t)i+1];
    bf16x8 o;
    o[0]=(bf16)a.x; o[1]=(bf16)a.y; o[2]=(bf16)a.z; o[3]=(bf16)a.w;
    o[4]=(bf16)b.x; o[5]=(bf16)b.y; o[6]=(bf16)b.z; o[7]=(bf16)b.w;
    *(bf16x8*)(dst + 8*(size_t)i) = o;
}

__global__ __launch_bounds__(256) void cvt_bf16_w4(const float* __restrict__ w0,
                                                   const float* __restrict__ w1,
                                                   const float* __restrict__ w2,
                                                   const float* __restrict__ w3,
                                                   bf16* __restrict__ d0,
                                                   bf16* __restrict__ d1,
                                                   bf16* __restrict__ d2,
                                                   bf16* __restrict__ d3) {
    int z = blockIdx.y;
    const float* src = (z==0)?w0:(z==1)?w1:(z==2)?w2:w3;
    bf16* dst = (z==0)?d0:(z==1)?d1:(z==2)?d2:d3;
    int i = blockIdx.x * 256 + threadIdx.x;
    const float4* s4 = (const float4*)src;
    float4 a = s4[2*(size_t)i], b = s4[2*(size_t)i+1];
    bf16x8 o;
    o[0]=(bf16)a.x; o[1]=(bf16)a.y; o[2]=(bf16)a.z; o[3]=(bf16)a.w;
    o[4]=(bf16)b.x; o[5]=(bf16)b.y; o[6]=(bf16)b.z; o[7]=(bf16)b.w;
    *(bf16x8*)(dst + 8*(size_t)i) = o;
}

// ---------------- QKV projection GEMM (round-11: exact round-8 kernel) ------
// Round-10 post-mortem: the z<2 transposed-MFMA epilogue (uniform branch
// INSIDE the K-loop -> duplicated 16-MFMA body) cost ~12 µs; the packed
// stores saved nothing (both patterns coalesce into the same 32B segments).
// Revert byte-exact to round 8: single MFMA orientation, scalar z<2 stores.
// 2-buf 32KB -> 5 blocks/CU (round-9 showed 3-buf/48KB costs ~11 µs: TLP-bound).
// z=0 -> Q (pre-scaled by 0.125*log2e) in (B,H,T,D); z=1 -> K; z=2 -> V^T.
__global__ __launch_bounds__(256) void gemm_qkv(const bf16* __restrict__ xb,
                                                const bf16* __restrict__ wqb,
                                                const bf16* __restrict__ wkb,
                                                const bf16* __restrict__ wvb,
                                                bf16* __restrict__ qo,
                                                bf16* __restrict__ ko,
                                                bf16* __restrict__ vto) {
    int z = blockIdx.z;
    const bf16* w = (z == 0) ? wqb : (z == 1) ? wkb : wvb;
    bf16* dst = (z == 0) ? qo : (z == 1) ? ko : vto;
    int mbase = blockIdx.x * 128;
    int nbase = blockIdx.y * 128;
    __shared__ bf16 As[2][128][32];   // UNPADDED: global_load_lds lane-contiguous
    __shared__ bf16 Bs[2][128][32];
    int tid  = threadIdx.x;
    int wave = tid >> 6, lane = tid & 63;
    int wm = (wave >> 1) * 64, wn = (wave & 1) * 64;
    int lr = lane & 15, lg = lane >> 4;
    int srow0 = tid >> 2, scol0 = tid & 3;
    int srow1 = (tid + 256) >> 2, scol1 = (tid + 256) & 3;
    const bf16* xa0 = xb + (size_t)(mbase + srow0) * C_ + scol0 * 8;
    const bf16* xa1 = xb + (size_t)(mbase + srow1) * C_ + scol1 * 8;
    const bf16* wa0 = w  + (size_t)(nbase + srow0) * C_ + scol0 * 8;
    const bf16* wa1 = w  + (size_t)(nbase + srow1) * C_ + scol1 * 8;
#define GSTAGE(kb_, cb_) do { \
        gl_lds16(xa0 + (kb_), &As[cb_][srow0][scol0 * 8]); \
        gl_lds16(xa1 + (kb_), &As[cb_][srow1][scol1 * 8]); \
        gl_lds16(wa0 + (kb_), &Bs[cb_][srow0][scol0 * 8]); \
        gl_lds16(wa1 + (kb_), &Bs[cb_][srow1][scol1 * 8]); \
    } while (0)
    f32x4 acc[4][4] = {};
    GSTAGE(0, 0);
    __syncthreads();               // drain DMA for tile 0
    int cur = 0;
    for (int kb = 0; kb < C_; kb += 32) {
        if (kb + 32 < C_) GSTAGE(kb + 32, cur ^ 1);   // DMA overlaps compute
        bf16x8 af[4], bfr[4];
        #pragma unroll
        for (int mt = 0; mt < 4; ++mt) af[mt]  = *(const bf16x8*)(&As[cur][wm + mt*16 + lr][lg*8]);
        #pragma unroll
        for (int nt = 0; nt < 4; ++nt) bfr[nt] = *(const bf16x8*)(&Bs[cur][wn + nt*16 + lr][lg*8]);
        #pragma unroll
        for (int mt = 0; mt < 4; ++mt)
            #pragma unroll
            for (int nt = 0; nt < 4; ++nt)
                acc[mt][nt] = __builtin_amdgcn_mfma_f32_16x16x32_bf16(af[mt], bfr[nt], acc[mt][nt], 0, 0, 0);
        __syncthreads();           // next-tile DMA landed + all reads of cur done
        cur ^= 1;
    }
#undef GSTAGE
    float sc = (z == 0) ? 0.18033688011112042f : 1.0f;  // 0.125*log2(e) folded into Q
    int m0 = mbase + wm + (lg << 2);
    int n0 = nbase + wn + lr;
    if (z < 2) {
        #pragma unroll
        for (int mt = 0; mt < 4; ++mt) {
            #pragma unroll
            for (int nt = 0; nt < 4; ++nt) {
                int n = n0 + nt * 16;
                int h = n >> 6, d = n & 63;
                #pragma unroll
                for (int r = 0; r < 4; ++r) {
                    int m = m0 + mt * 16 + r;
                    int b = m >> 12, t = m & 4095;
                    dst[(((size_t)b * H_ + h) * T_ + t) * 64 + d] = (bf16)(acc[mt][nt][r] * sc);
                }
            }
        }
    } else {
        #pragma unroll
        for (int mt = 0; mt < 4; ++mt) {
            int m = m0 + mt * 16;
            int b = m >> 12, t = m & 4095;
            #pragma unroll
            for (int nt = 0; nt < 4; ++nt) {
                int n = n0 + nt * 16;
                int h = n >> 6, d = n & 63;
                bf16x4 pk;
                #pragma unroll
                for (int r = 0; r < 4; ++r) pk[r] = (bf16)acc[mt][nt][r];
                *(bf16x4*)(dst + (((size_t)b * H_ + h) * 64 + d) * T_ + t) = pk;
            }
        }
    }
}

// ---------------- output projection GEMM (round-8 structure) ----------------
__global__ __launch_bounds__(256) void gemm_out(const bf16* __restrict__ ctx,
                                                const bf16* __restrict__ wob,
                                                float* __restrict__ out) {
    int mbase = blockIdx.x * 128;
    int nbase = blockIdx.y * 128;
    __shared__ bf16 As[2][128][32];
    __shared__ bf16 Bs[2][128][32];
    int tid  = threadIdx.x;
    int wave = tid >> 6, lane = tid & 63;
    int wm = (wave >> 1) * 64, wn = (wave & 1) * 64;
    int lr = lane & 15, lg = lane >> 4;
    int srow0 = tid >> 2, scol0 = tid & 3;
    int srow1 = (tid + 256) >> 2, scol1 = (tid + 256) & 3;
    const bf16* xa0 = ctx + (size_t)(mbase + srow0) * C_ + scol0 * 8;
    const bf16* xa1 = ctx + (size_t)(mbase + srow1) * C_ + scol1 * 8;
    const bf16* wa0 = wob + (size_t)(nbase + srow0) * C_ + scol0 * 8;
    const bf16* wa1 = wob + (size_t)(nbase + srow1) * C_ + scol1 * 8;
#define GSTAGE(kb_, cb_) do { \
        gl_lds16(xa0 + (kb_), &As[cb_][srow0][scol0 * 8]); \
        gl_lds16(xa1 + (kb_), &As[cb_][srow1][scol1 * 8]); \
        gl_lds16(wa0 + (kb_), &Bs[cb_][srow0][scol0 * 8]); \
        gl_lds16(wa1 + (kb_), &Bs[cb_][srow1][scol1 * 8]); \
    } while (0)
    f32x4 acc[4][4] = {};
    GSTAGE(0, 0);
    __syncthreads();
    int cur = 0;
    for (int kb = 0; kb < C_; kb += 32) {
        if (kb + 32 < C_) GSTAGE(kb + 32, cur ^ 1);
        bf16x8 af[4], bfr[4];
        #pragma unroll
        for (int mt = 0; mt < 4; ++mt) af[mt]  = *(const bf16x8*)(&As[cur][wm + mt*16 + lr][lg*8]);
        #pragma unroll
        for (int nt = 0; nt < 4; ++nt) bfr[nt] = *(const bf16x8*)(&Bs[cur][wn + nt*16 + lr][lg*8]);
        #pragma unroll
        for (int mt = 0; mt < 4; ++mt)
            #pragma unroll
            for (int nt = 0; nt < 4; ++nt)
                acc[mt][nt] = __builtin_amdgcn_mfma_f32_16x16x32_bf16(af[mt], bfr[nt], acc[mt][nt], 0, 0, 0);
        __syncthreads();
        cur ^= 1;
    }
#undef GSTAGE
    int m0 = mbase + wm + (lg << 2);
    int n0 = nbase + wn + lr;
    #pragma unroll
    for (int mt = 0; mt < 4; ++mt)
        #pragma unroll
        for (int nt = 0; nt < 4; ++nt)
            #pragma unroll
            for (int r = 0; r < 4; ++r)
                out[(size_t)(m0 + mt * 16 + r) * C_ + n0 + nt * 16] = acc[mt][nt][r];
}

// ---------------- causal flash attention (round-10 version, kept) -----------
// 86.6 µs: DMA-staged dbuf, XOR-swizzle (0 conflicts), fixed-max exp2
// softmax, in-register P via permlane, l-sum on the MFMA pipe (A=ones).
__device__ __forceinline__ void attn_store(const f32x4 (&o)[4], float l, bf16* __restrict__ ctx,
                                           int b, int qrow, int h, int lg) {
    float inv = 1.0f / l;
    #pragma unroll
    for (int dt = 0; dt < 4; ++dt) {
        bf16x4 pk;
        #pragma unroll
        for (int r = 0; r < 4; ++r) pk[r] = (bf16)(o[dt][r] * inv);
        *(bf16x4*)(ctx + ((size_t)b * T_ + qrow) * C_ + h * 64 + dt * 16 + lg * 4) = pk;
    }
}

__global__ __launch_bounds__(256) void attn(const bf16* __restrict__ q,
                                            const bf16* __restrict__ k,
                                            const bf16* __restrict__ vt,
                                            bf16* __restrict__ ctx) {
    int idx = blockIdx.x;          // 0..1535
    int qt = 63 - idx / 24;        // globally sorted descending work
    int bh = idx % 24;
    int b = bh / H_, h = bh % H_;
    int tid = threadIdx.x;
    int wave = tid >> 6, lane = tid & 63;
    int lr = lane & 15, lg = lane >> 4;

    __shared__ bf16 Ks[2][64][64]; // double-buffered K tile (keys x d), swizzled
    __shared__ bf16 Vs[2][64][64]; // double-buffered V^T tile (d x keys), swizzled

    const bf16* qp = q  + (size_t)bh * T_ * 64;
    const bf16* kp = k  + (size_t)bh * T_ * 64;
    const bf16* vp = vt + (size_t)bh * 64 * (size_t)T_;

    // staging: thread tid owns LDS 16B chunk (row r0, chunk c0) = linear tid*16;
    // source column pre-swizzled so LDS[row][j] = G[row][j ^ (row&7)]
    int r0 = tid >> 3, c0 = tid & 7;
    int cs = (c0 ^ (r0 & 7)) * 8;                    // swizzled source col (elems)
    const bf16* kstg = kp + (size_t)r0 * 64 + cs;
    const bf16* vstg = vp + (size_t)r0 * T_ + cs;

#define STAGE(kb_, cb_) do { \
        const bf16* ks_ = kstg + (size_t)(kb_) * 64 * 64; \
        const bf16* vs_ = vstg + (size_t)(kb_) * 64; \
        gl_lds16(ks_,                   &Ks[cb_][r0][c0 * 8]); \
        gl_lds16(ks_ + 32 * 64,         &Ks[cb_][32 + r0][c0 * 8]); \
        gl_lds16(vs_,                   &Vs[cb_][r0][c0 * 8]); \
        gl_lds16(vs_ + (size_t)32 * T_, &Vs[cb_][32 + r0][c0 * 8]); \
    } while (0)

    const float NEGINF = -__builtin_inff();

    int qb = qt * 64 + wave * 16;
    int n  = qt + 1;
    int qrow = qb + lr;

    // read-side swizzled chunk offsets (loop-invariant per lane)
    int sw = lr & 7;
    int col0 = (lg ^ sw) * 8;           // chunk c2=0: (0*4+lg) ^ (row&7)
    int col1 = ((4 | lg) ^ sw) * 8;     // chunk c2=1: (1*4+lg) ^ (row&7)

    bf16x8 qf[2];
    #pragma unroll
    for (int c = 0; c < 2; ++c)
        qf[c] = *(const bf16x8*)(qp + (size_t)(qb + lr) * 64 + c * 32 + lg * 8);

    // all-ones A-frag for the l-sum MFMA (bf16 1.0 = 0x3F80)
    u32x4 onep;
    onep[0] = 0x3F803F80u; onep[1] = 0x3F803F80u; onep[2] = 0x3F803F80u; onep[3] = 0x3F803F80u;
    bf16x8 ones = __builtin_bit_cast(bf16x8, onep);

    f32x4 o[4] = {};
    f32x4 lacc = {};
    const f32x4 fz = {};           // loop-invariant zero C operand

    STAGE(0, 0);
    __syncthreads();               // drain DMA for tile 0
    int cur = 0;

    for (int kb = 0; kb < n; ++kb) {
        int kv = kb * 64;
        if (kb + 1 < n) STAGE(kb + 1, cur ^ 1);   // DMA overlaps compute below

        // S^T = K Q^T : rows = keys (A-frag from LDS), cols = q (lane lr)
        f32x4 s[4];
        __builtin_amdgcn_s_setprio(1);
        #pragma unroll
        for (int nt = 0; nt < 4; ++nt) {
            bf16x8 kf0 = *(const bf16x8*)(&Ks[cur][nt * 16 + lr][col0]);
            s[nt] = __builtin_amdgcn_mfma_f32_16x16x32_bf16(kf0, qf[0], fz, 0, 0, 0);
        }
        #pragma unroll
        for (int nt = 0; nt < 4; ++nt) {
            bf16x8 kf1 = *(const bf16x8*)(&Ks[cur][nt * 16 + lr][col1]);
            s[nt] = __builtin_amdgcn_mfma_f32_16x16x32_bf16(kf1, qf[1], s[nt], 0, 0, 0);
        }
        __builtin_amdgcn_s_setprio(0);
        // causal mask (diagonal tile only; Q pre-scaled by 0.125*log2e)
        if (kb == qt) {
            #pragma unroll
            for (int nt = 0; nt < 4; ++nt)
                #pragma unroll
                for (int r = 0; r < 4; ++r) {
                    int key = kv + nt * 16 + lg * 4 + r;
                    s[nt][r] = (key > qrow) ? NEGINF : s[nt][r];
                }
        }
        // fixed-max softmax: p = exp2(s); l accumulated on the MFMA pipe below
        #pragma unroll
        for (int nt = 0; nt < 4; ++nt)
            #pragma unroll
            for (int r = 0; r < 4; ++r)
                s[nt][r] = __builtin_amdgcn_exp2f(s[nt][r]);
        // P: S-frag -> PV B-frag entirely in registers (no LDS round-trip)
        unsigned int dpk[8];
        #pragma unroll
        for (int nt = 0; nt < 4; ++nt) {
            dpk[2*nt]   = cvtpk(s[nt][0], s[nt][1]);
            dpk[2*nt+1] = cvtpk(s[nt][2], s[nt][3]);
        }
        unsigned int pw[2][4];
        #pragma unroll
        for (int c2 = 0; c2 < 2; ++c2)
            #pragma unroll
            for (int pr = 0; pr < 2; ++pr) {
                unsigned int x = dpk[4*c2 + pr], y = dpk[4*c2 + 2 + pr];
                pswap32_16(x, y);
                pw[c2][pr] = x;      // word pr   (keys c2*32+lg*8 + {2pr,2pr+1})
                pw[c2][2+pr] = y;    // word pr+2 (keys c2*32+lg*8 + {4+2pr,5+2pr})
            }
        // O^T += V^T P^T ; l += 1^T P  (A=ones row-sums P on the MFMA pipe)
        __builtin_amdgcn_s_setprio(1);
        #pragma unroll
        for (int c2 = 0; c2 < 2; ++c2) {
            u32x4 pt;
            pt[0] = pw[c2][0]; pt[1] = pw[c2][1]; pt[2] = pw[c2][2]; pt[3] = pw[c2][3];
            bf16x8 pf = __builtin_bit_cast(bf16x8, pt);
            int vcol = c2 ? col1 : col0;
            #pragma unroll
            for (int dt = 0; dt < 4; ++dt) {
                bf16x8 vfr = *(const bf16x8*)(&Vs[cur][dt * 16 + lr][vcol]);
                o[dt] = __builtin_amdgcn_mfma_f32_16x16x32_bf16(vfr, pf, o[dt], 0, 0, 0);
            }
            lacc = __builtin_amdgcn_mfma_f32_16x16x32_bf16(ones, pf, lacc, 0, 0, 0);
        }
        __builtin_amdgcn_s_setprio(0);

        __syncthreads();           // drains next-tile DMA + all waves done with cur
        cur ^= 1;
    }
#undef STAGE

    // lacc[r] = full sum over ALL keys of P[.][lr] (identical across rows/lg)
    attn_store(o, lacc[0], ctx, b, qrow, h, lg);
}

// ---------------- launch ----------------
extern "C" void kernel_launch(void* const* d_in, const int* in_sizes, int n_in,
                              void* d_out, int out_size, void* d_ws, size_t ws_size,
                              hipStream_t stream) {
    const float* x  = (const float*)d_in[0];
    const float* wq = (const float*)d_in[1];
    const float* wk = (const float*)d_in[2];
    const float* wv = (const float*)d_in[3];
    const float* wo = (const float*)d_in[4];
    float* out = (float*)d_out;

    char* ws = (char*)d_ws;
    const size_t SZ_XB = (size_t)MTOT * C_ * sizeof(bf16);
    const size_t SZ_W  = (size_t)C_ * C_ * sizeof(bf16);
    bf16* xb  = (bf16*)(ws);
    bf16* wqb = (bf16*)(ws + SZ_XB);
    bf16* wkb = (bf16*)(ws + SZ_XB + SZ_W);
    bf16* wvb = (bf16*)(ws + SZ_XB + 2 * SZ_W);
    bf16* wob = (bf16*)(ws + SZ_XB + 3 * SZ_W);
    bf16* qb  = (bf16*)(ws + SZ_XB + 4 * SZ_W);
    bf16* kb  = (bf16*)(ws + 2 * SZ_XB + 4 * SZ_W);
    bf16* vtb = (bf16*)(ws + 3 * SZ_XB + 4 * SZ_W);
    bf16* ctb = (bf16*)(ws + 4 * SZ_XB + 4 * SZ_W);

    cvt_bf16<<<3072, 256, 0, stream>>>(x, xb, MTOT * C_ / 8);
    cvt_bf16_w4<<<dim3(288, 4), 256, 0, stream>>>(wq, wk, wv, wo, wqb, wkb, wvb, wob);

    gemm_qkv<<<dim3(MTOT / 128, C_ / 128, 3), 256, 0, stream>>>(xb, wqb, wkb, wvb, qb, kb, vtb);
    attn<<<1536, 256, 0, stream>>>(qb, kb, vtb, ctb);
    gemm_out<<<dim3(MTOT / 128, C_ / 128), 256, 0, stream>>>(ctb, wob, out);
}

// Round 12
// 226.489 us; speedup vs baseline: 1.1118x; 1.0050x over previous
//
#include <hip/hip_runtime.h>
#include <hip/hip_bf16.h>

#define B_  2
#define T_  4096
#define C_  768
#define H_  12
#define D_  64
#define MTOT (B_*T_)   // 8192

typedef __bf16 bf16;
typedef __bf16 bf16x8 __attribute__((ext_vector_type(8)));
typedef __bf16 bf16x4 __attribute__((ext_vector_type(4)));
typedef float  f32x4  __attribute__((ext_vector_type(4)));
typedef unsigned int u32x4 __attribute__((ext_vector_type(4)));

// async global->LDS, 16B per lane; LDS dest must be wave-uniform base + lane*16
__device__ __forceinline__ void gl_lds16(const bf16* g, bf16* l) {
    __builtin_amdgcn_global_load_lds(
        (const __attribute__((address_space(1))) void*)g,
        (__attribute__((address_space(3))) void*)l, 16, 0, 0);
}

// ---- P redistribution via permlane-swap BUILTINS ----
__device__ __forceinline__ void pswap32_16(unsigned int& x, unsigned int& y) {
    auto r1 = __builtin_amdgcn_permlane32_swap(x, y, false, false);
    auto r2 = __builtin_amdgcn_permlane16_swap(r1[0], r1[1], false, false);
    x = r2[0]; y = r2[1];
}
__device__ __forceinline__ unsigned int cvtpk(float lo, float hi) {
    unsigned int r;
    asm("v_cvt_pk_bf16_f32 %0, %1, %2" : "=v"(r) : "v"(lo), "v"(hi));
    return r;
}

// ---------------- fp32 -> bf16 convert ----------------
__global__ __launch_bounds__(256) void cvt_bf16(const float* __restrict__ src,
                                                bf16* __restrict__ dst, int n8) {
    int i = blockIdx.x * 256 + threadIdx.x;
    if (i >= n8) return;
    const float4* s4 = (const float4*)src;
    float4 a = s4[2*(size_t)i], b = s4[2*(size_t)i+1];
    bf16x8 o;
    o[0]=(bf16)a.x; o[1]=(bf16)a.y; o[2]=(bf16)a.z; o[3]=(bf16)a.w;
    o[4]=(bf16)b.x; o[5]=(bf16)b.y; o[6]=(bf16)b.z; o[7]=(bf16)b.w;
    *(bf16x8*)(dst + 8*(size_t)i) = o;
}

__global__ __launch_bounds__(256) void cvt_bf16_w4(const float* __restrict__ w0,
                                                   const float* __restrict__ w1,
                                                   const float* __restrict__ w2,
                                                   const float* __restrict__ w3,
                                                   bf16* __restrict__ d0,
                                                   bf16* __restrict__ d1,
                                                   bf16* __restrict__ d2,
                                                   bf16* __restrict__ d3) {
    int z = blockIdx.y;
    const float* src = (z==0)?w0:(z==1)?w1:(z==2)?w2:w3;
    bf16* dst = (z==0)?d0:(z==1)?d1:(z==2)?d2:d3;
    int i = blockIdx.x * 256 + threadIdx.x;
    const float4* s4 = (const float4*)src;
    float4 a = s4[2*(size_t)i], b = s4[2*(size_t)i+1];
    bf16x8 o;
    o[0]=(bf16)a.x; o[1]=(bf16)a.y; o[2]=(bf16)a.z; o[3]=(bf16)a.w;
    o[4]=(bf16)b.x; o[5]=(bf16)b.y; o[6]=(bf16)b.z; o[7]=(bf16)b.w;
    *(bf16x8*)(dst + 8*(size_t)i) = o;
}

// ---------------- QKV projection GEMM (round-12: XCD-aware swizzle) ---------
// Round-11 traffic arithmetic: every block stages full A+B panels (392 KB);
// qkv aggregate = 1152 x 392KB = 451 MB in ~75 µs = 6 TB/s — AT the HBM/L3
// ceiling. xb is re-staged 18x (6 n-tiles x 3 z) and the 18 blocks sharing an
// A-panel are round-robin-scattered across all 8 XCDs -> every re-read misses
// the 4MB local L2. Fix (T1, bijective): id&7 = XCD; XCD k owns m-panels
// x in [8k,8k+8). Working set/XCD = A-slab 1.57MB + all W 3.5MB ~= L2 ->
// re-reads become local-L2 hits (34.5 TB/s agg). Pure index permutation.
// Loop/epilogue = round-8 proven structure (2-buf 32KB, 5 blocks/CU).
// z=0 -> Q (pre-scaled by 0.125*log2e) in (B,H,T,D); z=1 -> K; z=2 -> V^T.
__global__ __launch_bounds__(256) void gemm_qkv(const bf16* __restrict__ xb,
                                                const bf16* __restrict__ wqb,
                                                const bf16* __restrict__ wkb,
                                                const bf16* __restrict__ wvb,
                                                bf16* __restrict__ qo,
                                                bf16* __restrict__ ko,
                                                bf16* __restrict__ vto) {
    // XCD-aware remap: grid (64,6,3) -> linear id -> (bx, by, z)
    int id  = blockIdx.x + (blockIdx.y << 6) + blockIdx.z * 384;  // 0..1151
    int xcd = id & 7;
    int j   = id >> 3;                 // 0..143
    int bx  = xcd * 8 + j / 18;        // 0..63 : XCD k owns x in [8k,8k+8)
    int sub = j % 18;
    int by  = sub % 6;                 // 0..5
    int z   = sub / 6;                 // 0..2
    const bf16* w = (z == 0) ? wqb : (z == 1) ? wkb : wvb;
    bf16* dst = (z == 0) ? qo : (z == 1) ? ko : vto;
    int mbase = bx * 128;
    int nbase = by * 128;
    __shared__ bf16 As[2][128][32];   // UNPADDED: global_load_lds lane-contiguous
    __shared__ bf16 Bs[2][128][32];
    int tid  = threadIdx.x;
    int wave = tid >> 6, lane = tid & 63;
    int wm = (wave >> 1) * 64, wn = (wave & 1) * 64;
    int lr = lane & 15, lg = lane >> 4;
    int srow0 = tid >> 2, scol0 = tid & 3;
    int srow1 = (tid + 256) >> 2, scol1 = (tid + 256) & 3;
    const bf16* xa0 = xb + (size_t)(mbase + srow0) * C_ + scol0 * 8;
    const bf16* xa1 = xb + (size_t)(mbase + srow1) * C_ + scol1 * 8;
    const bf16* wa0 = w  + (size_t)(nbase + srow0) * C_ + scol0 * 8;
    const bf16* wa1 = w  + (size_t)(nbase + srow1) * C_ + scol1 * 8;
#define GSTAGE(kb_, cb_) do { \
        gl_lds16(xa0 + (kb_), &As[cb_][srow0][scol0 * 8]); \
        gl_lds16(xa1 + (kb_), &As[cb_][srow1][scol1 * 8]); \
        gl_lds16(wa0 + (kb_), &Bs[cb_][srow0][scol0 * 8]); \
        gl_lds16(wa1 + (kb_), &Bs[cb_][srow1][scol1 * 8]); \
    } while (0)
    f32x4 acc[4][4] = {};
    GSTAGE(0, 0);
    __syncthreads();               // drain DMA for tile 0
    int cur = 0;
    for (int kb = 0; kb < C_; kb += 32) {
        if (kb + 32 < C_) GSTAGE(kb + 32, cur ^ 1);   // DMA overlaps compute
        bf16x8 af[4], bfr[4];
        #pragma unroll
        for (int mt = 0; mt < 4; ++mt) af[mt]  = *(const bf16x8*)(&As[cur][wm + mt*16 + lr][lg*8]);
        #pragma unroll
        for (int nt = 0; nt < 4; ++nt) bfr[nt] = *(const bf16x8*)(&Bs[cur][wn + nt*16 + lr][lg*8]);
        #pragma unroll
        for (int mt = 0; mt < 4; ++mt)
            #pragma unroll
            for (int nt = 0; nt < 4; ++nt)
                acc[mt][nt] = __builtin_amdgcn_mfma_f32_16x16x32_bf16(af[mt], bfr[nt], acc[mt][nt], 0, 0, 0);
        __syncthreads();           // next-tile DMA landed + all reads of cur done
        cur ^= 1;
    }
#undef GSTAGE
    float sc = (z == 0) ? 0.18033688011112042f : 1.0f;  // 0.125*log2(e) folded into Q
    int m0 = mbase + wm + (lg << 2);
    int n0 = nbase + wn + lr;
    if (z < 2) {
        #pragma unroll
        for (int mt = 0; mt < 4; ++mt) {
            #pragma unroll
            for (int nt = 0; nt < 4; ++nt) {
                int n = n0 + nt * 16;
                int h = n >> 6, d = n & 63;
                #pragma unroll
                for (int r = 0; r < 4; ++r) {
                    int m = m0 + mt * 16 + r;
                    int b = m >> 12, t = m & 4095;
                    dst[(((size_t)b * H_ + h) * T_ + t) * 64 + d] = (bf16)(acc[mt][nt][r] * sc);
                }
            }
        }
    } else {
        #pragma unroll
        for (int mt = 0; mt < 4; ++mt) {
            int m = m0 + mt * 16;
            int b = m >> 12, t = m & 4095;
            #pragma unroll
            for (int nt = 0; nt < 4; ++nt) {
                int n = n0 + nt * 16;
                int h = n >> 6, d = n & 63;
                bf16x4 pk;
                #pragma unroll
                for (int r = 0; r < 4; ++r) pk[r] = (bf16)acc[mt][nt][r];
                *(bf16x4*)(dst + (((size_t)b * H_ + h) * 64 + d) * T_ + t) = pk;
            }
        }
    }
}

// ---------------- output projection GEMM (round-12: XCD-aware swizzle) ------
// Same T1 remap: grid (64,6) -> XCD k owns x in [8k,8k+8). Working set/XCD =
// ctx slab 1.57MB + wob 1.18MB = 2.75MB < 4MB L2 (fully fits).
__global__ __launch_bounds__(256) void gemm_out(const bf16* __restrict__ ctx,
                                                const bf16* __restrict__ wob,
                                                float* __restrict__ out) {
    int id  = blockIdx.x + (blockIdx.y << 6);   // 0..383
    int xcd = id & 7;
    int j   = id >> 3;                 // 0..47
    int bx  = xcd * 8 + j / 6;         // 0..63
    int by  = j % 6;                   // 0..5
    int mbase = bx * 128;
    int nbase = by * 128;
    __shared__ bf16 As[2][128][32];
    __shared__ bf16 Bs[2][128][32];
    int tid  = threadIdx.x;
    int wave = tid >> 6, lane = tid & 63;
    int wm = (wave >> 1) * 64, wn = (wave & 1) * 64;
    int lr = lane & 15, lg = lane >> 4;
    int srow0 = tid >> 2, scol0 = tid & 3;
    int srow1 = (tid + 256) >> 2, scol1 = (tid + 256) & 3;
    const bf16* xa0 = ctx + (size_t)(mbase + srow0) * C_ + scol0 * 8;
    const bf16* xa1 = ctx + (size_t)(mbase + srow1) * C_ + scol1 * 8;
    const bf16* wa0 = wob + (size_t)(nbase + srow0) * C_ + scol0 * 8;
    const bf16* wa1 = wob + (size_t)(nbase + srow1) * C_ + scol1 * 8;
#define GSTAGE(kb_, cb_) do { \
        gl_lds16(xa0 + (kb_), &As[cb_][srow0][scol0 * 8]); \
        gl_lds16(xa1 + (kb_), &As[cb_][srow1][scol1 * 8]); \
        gl_lds16(wa0 + (kb_), &Bs[cb_][srow0][scol0 * 8]); \
        gl_lds16(wa1 + (kb_), &Bs[cb_][srow1][scol1 * 8]); \
    } while (0)
    f32x4 acc[4][4] = {};
    GSTAGE(0, 0);
    __syncthreads();
    int cur = 0;
    for (int kb = 0; kb < C_; kb += 32) {
        if (kb + 32 < C_) GSTAGE(kb + 32, cur ^ 1);
        bf16x8 af[4], bfr[4];
        #pragma unroll
        for (int mt = 0; mt < 4; ++mt) af[mt]  = *(const bf16x8*)(&As[cur][wm + mt*16 + lr][lg*8]);
        #pragma unroll
        for (int nt = 0; nt < 4; ++nt) bfr[nt] = *(const bf16x8*)(&Bs[cur][wn + nt*16 + lr][lg*8]);
        #pragma unroll
        for (int mt = 0; mt < 4; ++mt)
            #pragma unroll
            for (int nt = 0; nt < 4; ++nt)
                acc[mt][nt] = __builtin_amdgcn_mfma_f32_16x16x32_bf16(af[mt], bfr[nt], acc[mt][nt], 0, 0, 0);
        __syncthreads();
        cur ^= 1;
    }
#undef GSTAGE
    int m0 = mbase + wm + (lg << 2);
    int n0 = nbase + wn + lr;
    #pragma unroll
    for (int mt = 0; mt < 4; ++mt)
        #pragma unroll
        for (int nt = 0; nt < 4; ++nt)
            #pragma unroll
            for (int r = 0; r < 4; ++r)
                out[(size_t)(m0 + mt * 16 + r) * C_ + n0 + nt * 16] = acc[mt][nt][r];
}

// ---------------- causal flash attention (round-10 version, kept) -----------
// 87 µs: DMA-staged dbuf, XOR-swizzle (0 conflicts), fixed-max exp2 softmax,
// in-register P via permlane, l-sum on the MFMA pipe (A=ones).
// bh%8 already gives per-XCD K/V locality (FETCH ~= compulsory).
__device__ __forceinline__ void attn_store(const f32x4 (&o)[4], float l, bf16* __restrict__ ctx,
                                           int b, int qrow, int h, int lg) {
    float inv = 1.0f / l;
    #pragma unroll
    for (int dt = 0; dt < 4; ++dt) {
        bf16x4 pk;
        #pragma unroll
        for (int r = 0; r < 4; ++r) pk[r] = (bf16)(o[dt][r] * inv);
        *(bf16x4*)(ctx + ((size_t)b * T_ + qrow) * C_ + h * 64 + dt * 16 + lg * 4) = pk;
    }
}

__global__ __launch_bounds__(256) void attn(const bf16* __restrict__ q,
                                            const bf16* __restrict__ k,
                                            const bf16* __restrict__ vt,
                                            bf16* __restrict__ ctx) {
    int idx = blockIdx.x;          // 0..1535
    int qt = 63 - idx / 24;        // globally sorted descending work
    int bh = idx % 24;
    int b = bh / H_, h = bh % H_;
    int tid = threadIdx.x;
    int wave = tid >> 6, lane = tid & 63;
    int lr = lane & 15, lg = lane >> 4;

    __shared__ bf16 Ks[2][64][64]; // double-buffered K tile (keys x d), swizzled
    __shared__ bf16 Vs[2][64][64]; // double-buffered V^T tile (d x keys), swizzled

    const bf16* qp = q  + (size_t)bh * T_ * 64;
    const bf16* kp = k  + (size_t)bh * T_ * 64;
    const bf16* vp = vt + (size_t)bh * 64 * (size_t)T_;

    // staging: thread tid owns LDS 16B chunk (row r0, chunk c0) = linear tid*16;
    // source column pre-swizzled so LDS[row][j] = G[row][j ^ (row&7)]
    int r0 = tid >> 3, c0 = tid & 7;
    int cs = (c0 ^ (r0 & 7)) * 8;                    // swizzled source col (elems)
    const bf16* kstg = kp + (size_t)r0 * 64 + cs;
    const bf16* vstg = vp + (size_t)r0 * T_ + cs;

#define STAGE(kb_, cb_) do { \
        const bf16* ks_ = kstg + (size_t)(kb_) * 64 * 64; \
        const bf16* vs_ = vstg + (size_t)(kb_) * 64; \
        gl_lds16(ks_,                   &Ks[cb_][r0][c0 * 8]); \
        gl_lds16(ks_ + 32 * 64,         &Ks[cb_][32 + r0][c0 * 8]); \
        gl_lds16(vs_,                   &Vs[cb_][r0][c0 * 8]); \
        gl_lds16(vs_ + (size_t)32 * T_, &Vs[cb_][32 + r0][c0 * 8]); \
    } while (0)

    const float NEGINF = -__builtin_inff();

    int qb = qt * 64 + wave * 16;
    int n  = qt + 1;
    int qrow = qb + lr;

    // read-side swizzled chunk offsets (loop-invariant per lane)
    int sw = lr & 7;
    int col0 = (lg ^ sw) * 8;           // chunk c2=0: (0*4+lg) ^ (row&7)
    int col1 = ((4 | lg) ^ sw) * 8;     // chunk c2=1: (1*4+lg) ^ (row&7)

    bf16x8 qf[2];
    #pragma unroll
    for (int c = 0; c < 2; ++c)
        qf[c] = *(const bf16x8*)(qp + (size_t)(qb + lr) * 64 + c * 32 + lg * 8);

    // all-ones A-frag for the l-sum MFMA (bf16 1.0 = 0x3F80)
    u32x4 onep;
    onep[0] = 0x3F803F80u; onep[1] = 0x3F803F80u; onep[2] = 0x3F803F80u; onep[3] = 0x3F803F80u;
    bf16x8 ones = __builtin_bit_cast(bf16x8, onep);

    f32x4 o[4] = {};
    f32x4 lacc = {};
    const f32x4 fz = {};           // loop-invariant zero C operand

    STAGE(0, 0);
    __syncthreads();               // drain DMA for tile 0
    int cur = 0;

    for (int kb = 0; kb < n; ++kb) {
        int kv = kb * 64;
        if (kb + 1 < n) STAGE(kb + 1, cur ^ 1);   // DMA overlaps compute below

        // S^T = K Q^T : rows = keys (A-frag from LDS), cols = q (lane lr)
        f32x4 s[4];
        __builtin_amdgcn_s_setprio(1);
        #pragma unroll
        for (int nt = 0; nt < 4; ++nt) {
            bf16x8 kf0 = *(const bf16x8*)(&Ks[cur][nt * 16 + lr][col0]);
            s[nt] = __builtin_amdgcn_mfma_f32_16x16x32_bf16(kf0, qf[0], fz, 0, 0, 0);
        }
        #pragma unroll
        for (int nt = 0; nt < 4; ++nt) {
            bf16x8 kf1 = *(const bf16x8*)(&Ks[cur][nt * 16 + lr][col1]);
            s[nt] = __builtin_amdgcn_mfma_f32_16x16x32_bf16(kf1, qf[1], s[nt], 0, 0, 0);
        }
        __builtin_amdgcn_s_setprio(0);
        // causal mask (diagonal tile only; Q pre-scaled by 0.125*log2e)
        if (kb == qt) {
            #pragma unroll
            for (int nt = 0; nt < 4; ++nt)
                #pragma unroll
                for (int r = 0; r < 4; ++r) {
                    int key = kv + nt * 16 + lg * 4 + r;
                    s[nt][r] = (key > qrow) ? NEGINF : s[nt][r];
                }
        }
        // fixed-max softmax: p = exp2(s); l accumulated on the MFMA pipe below
        #pragma unroll
        for (int nt = 0; nt < 4; ++nt)
            #pragma unroll
            for (int r = 0; r < 4; ++r)
                s[nt][r] = __builtin_amdgcn_exp2f(s[nt][r]);
        // P: S-frag -> PV B-frag entirely in registers (no LDS round-trip)
        unsigned int dpk[8];
        #pragma unroll
        for (int nt = 0; nt < 4; ++nt) {
            dpk[2*nt]   = cvtpk(s[nt][0], s[nt][1]);
            dpk[2*nt+1] = cvtpk(s[nt][2], s[nt][3]);
        }
        unsigned int pw[2][4];
        #pragma unroll
        for (int c2 = 0; c2 < 2; ++c2)
            #pragma unroll
            for (int pr = 0; pr < 2; ++pr) {
                unsigned int x = dpk[4*c2 + pr], y = dpk[4*c2 + 2 + pr];
                pswap32_16(x, y);
                pw[c2][pr] = x;      // word pr   (keys c2*32+lg*8 + {2pr,2pr+1})
                pw[c2][2+pr] = y;    // word pr+2 (keys c2*32+lg*8 + {4+2pr,5+2pr})
            }
        // O^T += V^T P^T ; l += 1^T P  (A=ones row-sums P on the MFMA pipe)
        __builtin_amdgcn_s_setprio(1);
        #pragma unroll
        for (int c2 = 0; c2 < 2; ++c2) {
            u32x4 pt;
            pt[0] = pw[c2][0]; pt[1] = pw[c2][1]; pt[2] = pw[c2][2]; pt[3] = pw[c2][3];
            bf16x8 pf = __builtin_bit_cast(bf16x8, pt);
            int vcol = c2 ? col1 : col0;
            #pragma unroll
            for (int dt = 0; dt < 4; ++dt) {
                bf16x8 vfr = *(const bf16x8*)(&Vs[cur][dt * 16 + lr][vcol]);
                o[dt] = __builtin_amdgcn_mfma_f32_16x16x32_bf16(vfr, pf, o[dt], 0, 0, 0);
            }
            lacc = __builtin_amdgcn_mfma_f32_16x16x32_bf16(ones, pf, lacc, 0, 0, 0);
        }
        __builtin_amdgcn_s_setprio(0);

        __syncthreads();           // drains next-tile DMA + all waves done with cur
        cur ^= 1;
    }
#undef STAGE

    // lacc[r] = full sum over ALL keys of P[.][lr] (identical across rows/lg)
    attn_store(o, lacc[0], ctx, b, qrow, h, lg);
}

// ---------------- launch ----------------
extern "C" void kernel_launch(void* const* d_in, const int* in_sizes, int n_in,
                              void* d_out, int out_size, void* d_ws, size_t ws_size,
                              hipStream_t stream) {
    const float* x  = (const float*)d_in[0];
    const float* wq = (const float*)d_in[1];
    const float* wk = (const float*)d_in[2];
    const float* wv = (const float*)d_in[3];
    const float* wo = (const float*)d_in[4];
    float* out = (float*)d_out;

    char* ws = (char*)d_ws;
    const size_t SZ_XB = (size_t)MTOT * C_ * sizeof(bf16);
    const size_t SZ_W  = (size_t)C_ * C_ * sizeof(bf16);
    bf16* xb  = (bf16*)(ws);
    bf16* wqb = (bf16*)(ws + SZ_XB);
    bf16* wkb = (bf16*)(ws + SZ_XB + SZ_W);
    bf16* wvb = (bf16*)(ws + SZ_XB + 2 * SZ_W);
    bf16* wob = (bf16*)(ws + SZ_XB + 3 * SZ_W);
    bf16* qb  = (bf16*)(ws + SZ_XB + 4 * SZ_W);
    bf16* kb  = (bf16*)(ws + 2 * SZ_XB + 4 * SZ_W);
    bf16* vtb = (bf16*)(ws + 3 * SZ_XB + 4 * SZ_W);
    bf16* ctb = (bf16*)(ws + 4 * SZ_XB + 4 * SZ_W);

    cvt_bf16<<<3072, 256, 0, stream>>>(x, xb, MTOT * C_ / 8);
    cvt_bf16_w4<<<dim3(288, 4), 256, 0, stream>>>(wq, wk, wv, wo, wqb, wkb, wvb, wob);

    gemm_qkv<<<dim3(MTOT / 128, C_ / 128, 3), 256, 0, stream>>>(xb, wqb, wkb, wvb, qb, kb, vtb);
    attn<<<1536, 256, 0, stream>>>(qb, kb, vtb, ctb);
    gemm_out<<<dim3(MTOT / 128, C_ / 128), 256, 0, stream>>>(ctb, wob, out);
}